// Round 2
// baseline (539.657 us; speedup 1.0000x reference)
//
#include <hip/hip_runtime.h>

#define TZ 128      // TOKEN_Z
#define JT 256      // j-tile per block
#define R_MAX 32
#define S_MAX 2

typedef float v4f __attribute__((ext_vector_type(4)));

// W row offsets: W_pos = rows [0,66), W_tok = rows [66,132), w_ent = row 132,
// W_ch = rows [133,139)

__global__ __launch_bounds__(256) void relpos_kernel(
    const int* __restrict__ asym, const int* __restrict__ resi,
    const int* __restrict__ ent,  const int* __restrict__ tok,
    const int* __restrict__ sym,  const int* __restrict__ cyc,
    const float* __restrict__ W,  float* __restrict__ out, int L)
{
    __shared__ unsigned int sidx[JT];

    const int i   = blockIdx.x;
    const int j0  = blockIdx.y * JT;
    const int tid = threadIdx.x;

    // ---- phase 1: per-j packed table indices (one j per thread) ----
    {
        const int j  = j0 + tid;
        const int ai = asym[i], aj = asym[j];
        const int ri = resi[i], rj = resi[j];
        const int ei = ent[i],  ej = ent[j];
        const int ti = tok[i],  tj = tok[j];
        const int si = sym[i],  sj = sym[j];
        const int cj = cyc[j];

        const bool same_chain = (ai == aj);
        const bool same_res   = (ri == rj);
        const bool same_ent   = (ei == ej);

        int rel = ri - rj;
        const int period = (cj > 0) ? cj : 10000;
        // jnp.round = round-half-even = rintf; astype(int) = trunc toward 0
        const float q = rintf((float)rel / (float)period);
        rel -= (int)((float)period * q);

        int dr = rel + R_MAX;
        dr = dr < 0 ? 0 : (dr > 2 * R_MAX ? 2 * R_MAX : dr);
        if (!same_chain) dr = 2 * R_MAX + 1;

        int dt = ti - tj + R_MAX;
        dt = dt < 0 ? 0 : (dt > 2 * R_MAX ? 2 * R_MAX : dt);
        if (!(same_chain && same_res)) dt = 2 * R_MAX + 1;

        int dc = si - sj + S_MAX;
        dc = dc < 0 ? 0 : (dc > 2 * S_MAX ? 2 * S_MAX : dc);
        if (same_chain) dc = 2 * S_MAX + 1;

        sidx[tid] = (unsigned)dr | ((unsigned)dt << 8) | ((unsigned)dc << 16)
                  | ((unsigned)(same_ent ? 1u : 0u) << 24);
    }
    __syncthreads();

    // ---- phase 2: gather + sum, 8 j per iteration, float4 over z ----
    const int zq = tid & 31;   // float4 chunk of z (32 chunks * 4 = 128)
    const int jr = tid >> 5;   // 0..7

    const v4f* __restrict__ Wv = (const v4f*)W;        // row r -> Wv[r*32 + zq]
    const v4f we = Wv[132 * 32 + zq];                  // w_ent fragment (regs)

    v4f* __restrict__ outv = (v4f*)(out + ((size_t)i * (size_t)L + (size_t)j0) * TZ);

    #pragma unroll 4
    for (int it = 0; it < JT / 8; ++it) {
        const int jl = it * 8 + jr;
        const unsigned pk = sidx[jl];
        const int dr = pk & 0xFF;
        const int dt = (pk >> 8) & 0xFF;
        const int dc = (pk >> 16) & 0xFF;
        const float se = (pk >> 24) ? 1.0f : 0.0f;

        const v4f a = Wv[dr * 32 + zq];
        const v4f b = Wv[(66 + dt) * 32 + zq];
        const v4f c = Wv[(133 + dc) * 32 + zq];

        const v4f r = a + b + c + se * we;

        // contiguous across the block: v4f index = jl*32 + zq = it*256 + tid
        __builtin_nontemporal_store(r, &outv[jl * 32 + zq]);
    }
}

extern "C" void kernel_launch(void* const* d_in, const int* in_sizes, int n_in,
                              void* d_out, int out_size, void* d_ws, size_t ws_size,
                              hipStream_t stream) {
    const int* asym = (const int*)d_in[0];
    const int* resi = (const int*)d_in[1];
    const int* ent  = (const int*)d_in[2];
    const int* tok  = (const int*)d_in[3];
    const int* sym  = (const int*)d_in[4];
    const int* cyc  = (const int*)d_in[5];
    const float* W  = (const float*)d_in[6];
    float* out      = (float*)d_out;

    const int L = in_sizes[0];          // B=1, L=1024
    dim3 grid(L, L / JT);
    dim3 block(256);
    relpos_kernel<<<grid, block, 0, stream>>>(asym, resi, ent, tok, sym, cyc, W, out, L);
}